// Round 1
// baseline (200.877 us; speedup 1.0000x reference)
//
#include <hip/hip_runtime.h>

typedef _Float16 f16;
typedef _Float16 f16x4 __attribute__((ext_vector_type(4)));
typedef _Float16 f16x8 __attribute__((ext_vector_type(8)));
typedef float f32x4 __attribute__((ext_vector_type(4)));

#define LOG2E 1.4426950408889634f

// ---------------- K0: transpose x[b][2048][256] -> xt[b][256][2048] (fp16) ---
__global__ __launch_bounds__(256) void k_transpose(const float* __restrict__ x,
                                                   f16* __restrict__ xt) {
  __shared__ f16 tile[64][65];
  int n0 = blockIdx.x * 64;
  int d0 = blockIdx.y * 64;
  int b  = blockIdx.z;
  int t = threadIdx.x;
  int colr = t & 63, rowg = t >> 6;
#pragma unroll
  for (int r = 0; r < 16; ++r) {
    int row = r * 4 + rowg;
    tile[row][colr] = (f16)x[(b * 2048 + n0 + row) * 256 + d0 + colr];
  }
  __syncthreads();
#pragma unroll
  for (int r = 0; r < 16; ++r) {
    int drow = r * 4 + rowg;
    xt[(b * 256 + d0 + drow) * 2048 + n0 + colr] = tile[colr][drow];
  }
}

// ---------------- K1: Q/K projections (both streams), fp16 MFMA GEMM --------
// Out layout: Q*/K* as [b*8+h][2048][32] fp16.
__global__ __launch_bounds__(256) void k_proj(const float* __restrict__ x,
    const float* __restrict__ af, const float* __restrict__ Wq,
    const float* __restrict__ Wa, f16* __restrict__ Qs, f16* __restrict__ Ks,
    f16* __restrict__ Qa, f16* __restrict__ Ka) {
  __shared__ f16 Alds[64][264];   // pad +8: 528B pitch, 16B aligned
  __shared__ f16 Wlds[64][264];   // W^T tile: [col][k]
  int mt = blockIdx.x, nt = blockIdx.y, s = blockIdx.z;
  const float* A = s ? af : x;
  const float* W = s ? Wa : Wq;
  f16* Qd = s ? Qa : Qs;
  f16* Kd = s ? Ka : Ks;
  int t = threadIdx.x;
  int m0 = mt * 64, n0 = nt * 64;
  {  // stage A rows m0..m0+63, all K=256 (fp32 -> fp16)
    int row = t >> 2, cb = (t & 3) * 64;
    const float* src = A + (m0 + row) * 256 + cb;
#pragma unroll
    for (int r = 0; r < 16; ++r) {
      float4 v = *(const float4*)(src + r * 4);
      f16x4 hv = { (f16)v.x, (f16)v.y, (f16)v.z, (f16)v.w };
      *(f16x4*)&Alds[row][cb + r * 4] = hv;
    }
  }
  {  // stage W^T: Wlds[c][k] = W[k][n0+c]  (only Q|K cols 0..511 used)
    int k0 = t >> 4, c4 = (t & 15) * 4;
#pragma unroll
    for (int r = 0; r < 16; ++r) {
      int k = k0 + r * 16;
      float4 v = *(const float4*)(W + k * 768 + n0 + c4);
      Wlds[c4 + 0][k] = (f16)v.x;
      Wlds[c4 + 1][k] = (f16)v.y;
      Wlds[c4 + 2][k] = (f16)v.z;
      Wlds[c4 + 3][k] = (f16)v.w;
    }
  }
  __syncthreads();
  int wv = t >> 6, ln = t & 63, cl = ln & 15, g = ln >> 4;
  f32x4 z4 = {0.f, 0.f, 0.f, 0.f};
  f32x4 acc[4] = {z4, z4, z4, z4};
#pragma unroll
  for (int k32 = 0; k32 < 8; ++k32) {
    f16x8 a = *(const f16x8*)&Alds[wv * 16 + cl][k32 * 32 + g * 8];
#pragma unroll
    for (int n4 = 0; n4 < 4; ++n4) {
      f16x8 bf = *(const f16x8*)&Wlds[n4 * 16 + cl][k32 * 32 + g * 8];
      acc[n4] = __builtin_amdgcn_mfma_f32_16x16x32_f16(a, bf, acc[n4], 0, 0, 0);
    }
  }
  // C/D layout: col = lane&15 (n), row = g*4+r (m)
#pragma unroll
  for (int n4 = 0; n4 < 4; ++n4) {
    int c = n0 + n4 * 16 + cl;            // global col 0..511 (Q:0-255 K:256-511)
    int head = (c & 255) >> 5, d = c & 31;
    f16* dst = (c < 256) ? Qd : Kd;
#pragma unroll
    for (int r = 0; r < 4; ++r) {
      int m = m0 + wv * 16 + g * 4 + r;
      int bb = m >> 11, nn = m & 2047;
      dst[((bb * 8 + head) * 2048 + nn) * 32 + d] = (f16)acc[n4][r];
    }
  }
}

// ---------------- K2: fused dual-score flash attention ----------------------
// WG = 4 waves, 64 q-rows (16/wave). KV tiles of 64 keys. S^T formulation.
__global__ __launch_bounds__(256, 2) void k_flash(const f16* __restrict__ Qs,
    const f16* __restrict__ Ks, const f16* __restrict__ Qa,
    const f16* __restrict__ Ka, const f16* __restrict__ xt,
    float* __restrict__ out, float* __restrict__ out_cls) {
  __shared__ f16 KaL[64][40];      // 80B pitch (20 banks) -> balanced b128 reads
  __shared__ f16 KsL[64][40];
  __shared__ f16 XtL[256][72];     // 144B pitch, 16B aligned
  __shared__ f16 PL[4][16][72];    // per-wave P round-trip
  int qt = blockIdx.x, h = blockIdx.y, b = blockIdx.z;
  int bh = b * 8 + h;
  int t = threadIdx.x, wv = t >> 6, ln = t & 63, cl = ln & 15, g = ln >> 4;
  int qrow0 = qt * 64 + wv * 16;
  // Q fragments (B-operand for S^T): lane holds Q[i=cl][d = g*8..g*8+7]
  f16x8 qsf = *(const f16x8*)&Qs[(bh * 2048 + qrow0 + cl) * 32 + g * 8];
  f16x8 qaf = *(const f16x8*)&Qa[(bh * 2048 + qrow0 + cl) * 32 + g * 8];
  f32x4 z4 = {0.f, 0.f, 0.f, 0.f};
  f32x4 acc[16];
#pragma unroll
  for (int i = 0; i < 16; ++i) acc[i] = z4;
  float m_run = -__builtin_inff(), l_run = 0.f;
  int krow = t >> 2, koff = (t & 3) * 8;
  const f16* kaSrc = Ka + (bh * 2048 + krow) * 32 + koff;
  const f16* ksSrc = Ks + (bh * 2048 + krow) * 32 + koff;
  const f16* xsrc = xt + (b * 256 + t) * 2048;

  for (int kt = 0; kt < 32; ++kt) {
    __syncthreads();   // protect LDS vs previous iteration's reads
    *(f16x8*)&KaL[krow][koff] = *(const f16x8*)(kaSrc + kt * 64 * 32);
    *(f16x8*)&KsL[krow][koff] = *(const f16x8*)(ksSrc + kt * 64 * 32);
    {
      const f16* sx = xsrc + kt * 64;
      f16x8* drow = (f16x8*)&XtL[t][0];
#pragma unroll
      for (int r = 0; r < 8; ++r) drow[r] = *(const f16x8*)(sx + r * 8);
    }
    __syncthreads();
    // --- dual QK^T: S^T[j][i] tiles (A = K-frag, B = Q-frag) ---
    float p[16];
    float tmax = -__builtin_inff();
#pragma unroll
    for (int jt = 0; jt < 4; ++jt) {
      f16x8 kaf = *(const f16x8*)&KaL[jt * 16 + cl][g * 8];
      f16x8 ksf = *(const f16x8*)&KsL[jt * 16 + cl][g * 8];
      f32x4 za = __builtin_amdgcn_mfma_f32_16x16x32_f16(kaf, qaf, z4, 0, 0, 0);
      f32x4 zs = __builtin_amdgcn_mfma_f32_16x16x32_f16(ksf, qsf, z4, 0, 0, 0);
#pragma unroll
      for (int r = 0; r < 4; ++r) {
        float sv = za[r] * zs[r] * (1.f / 32.f);   // scale^2 = 1/d_head
        p[jt * 4 + r] = sv;
        tmax = fmaxf(tmax, sv);
      }
    }
    // row stats for i = cl (reduce over j = regs + quad-groups)
    tmax = fmaxf(tmax, __shfl_xor(tmax, 16, 64));
    tmax = fmaxf(tmax, __shfl_xor(tmax, 32, 64));
    float m_new = fmaxf(m_run, tmax);
    float alpha = exp2f((m_run - m_new) * LOG2E);
    float lsum = 0.f;
#pragma unroll
    for (int q = 0; q < 16; ++q) {
      p[q] = exp2f((p[q] - m_new) * LOG2E);
      lsum += p[q];
    }
    lsum += __shfl_xor(lsum, 16, 64);
    lsum += __shfl_xor(lsum, 32, 64);
    l_run = l_run * alpha + lsum;
    m_run = m_new;
    // rescale O acc: O rows i = g*4+r, alpha lives at lane i (i<16)
    float af4[4];
#pragma unroll
    for (int r = 0; r < 4; ++r) af4[r] = __shfl(alpha, g * 4 + r, 64);
#pragma unroll
    for (int dt = 0; dt < 16; ++dt)
#pragma unroll
      for (int r = 0; r < 4; ++r) acc[dt][r] *= af4[r];
    // P -> LDS (C-layout -> A-operand layout round trip)
#pragma unroll
    for (int jt = 0; jt < 4; ++jt) {
      f16x4 pk = { (f16)p[jt * 4 + 0], (f16)p[jt * 4 + 1],
                   (f16)p[jt * 4 + 2], (f16)p[jt * 4 + 3] };
      *(f16x4*)&PL[wv][cl][jt * 16 + g * 4] = pk;
    }
    // --- PV: O[i][dd] += P[i][j] * Xt[dd][j] ---
#pragma unroll
    for (int k32 = 0; k32 < 2; ++k32) {
      f16x8 pf = *(const f16x8*)&PL[wv][cl][k32 * 32 + g * 8];
#pragma unroll
      for (int dt = 0; dt < 16; ++dt) {
        f16x8 xf = *(const f16x8*)&XtL[dt * 16 + cl][k32 * 32 + g * 8];
        acc[dt] = __builtin_amdgcn_mfma_f32_16x16x32_f16(pf, xf, acc[dt], 0, 0, 0);
      }
    }
  }
  // epilogue: normalize + store
  float lf[4];
#pragma unroll
  for (int r = 0; r < 4; ++r) lf[r] = __shfl(l_run, g * 4 + r, 64);
#pragma unroll
  for (int dt = 0; dt < 16; ++dt) {
    int col = h * 256 + dt * 16 + cl;
#pragma unroll
    for (int r = 0; r < 4; ++r) {
      int qrow = qrow0 + g * 4 + r;
      float v = acc[dt][r] / lf[r];
      out[(b * 2048 + qrow) * 2048 + col] = v;
      if (qrow == 0) out_cls[b * 2048 + col] = v;   // output 1: out[:,0]
    }
  }
}

// ---------------- K3: attention probs for query row 0 (output 2) ------------
__global__ __launch_bounds__(256) void k_attn0(const f16* __restrict__ Qs,
    const f16* __restrict__ Ks, const f16* __restrict__ Qa,
    const f16* __restrict__ Ka, float* __restrict__ dst) {
  __shared__ float qa_s[32], qs_s[32];
  __shared__ float red[256];
  int h = blockIdx.x, b = blockIdx.y, bh = b * 8 + h;
  int t = threadIdx.x;
  if (t < 32) {
    qa_s[t] = (float)Qa[bh * 2048 * 32 + t];
    qs_s[t] = (float)Qs[bh * 2048 * 32 + t];
  }
  __syncthreads();
  float sv[8];
#pragma unroll
  for (int r = 0; r < 8; ++r) {
    int j = r * 256 + t;
    const f16x8* ka8 = (const f16x8*)&Ka[(bh * 2048 + j) * 32];
    const f16x8* ks8 = (const f16x8*)&Ks[(bh * 2048 + j) * 32];
    float da = 0.f, ds = 0.f;
#pragma unroll
    for (int c = 0; c < 4; ++c) {
      f16x8 va = ka8[c], vs = ks8[c];
#pragma unroll
      for (int d = 0; d < 8; ++d) {
        da += qa_s[c * 8 + d] * (float)va[d];
        ds += qs_s[c * 8 + d] * (float)vs[d];
      }
    }
    sv[r] = da * ds * (1.f / 32.f);
  }
  float mx = sv[0];
#pragma unroll
  for (int r = 1; r < 8; ++r) mx = fmaxf(mx, sv[r]);
  red[t] = mx;
  __syncthreads();
  for (int st = 128; st > 0; st >>= 1) {
    if (t < st) red[t] = fmaxf(red[t], red[t + st]);
    __syncthreads();
  }
  float m = red[0];
  __syncthreads();
  float e[8], sum = 0.f;
#pragma unroll
  for (int r = 0; r < 8; ++r) {
    e[r] = exp2f((sv[r] - m) * LOG2E);
    sum += e[r];
  }
  red[t] = sum;
  __syncthreads();
  for (int st = 128; st > 0; st >>= 1) {
    if (t < st) red[t] += red[t + st];
    __syncthreads();
  }
  float l = red[0];
#pragma unroll
  for (int r = 0; r < 8; ++r)
    dst[b * 16384 + h * 2048 + r * 256 + t] = e[r] / l;
}

extern "C" void kernel_launch(void* const* d_in, const int* in_sizes, int n_in,
                              void* d_out, int out_size, void* d_ws, size_t ws_size,
                              hipStream_t stream) {
  const float* x  = (const float*)d_in[0];
  const float* af = (const float*)d_in[1];
  const float* Wq = (const float*)d_in[2];
  const float* Wa = (const float*)d_in[3];
  // ws layout (fp16): Qs | Ks | Qa | Ka | xt   (5 x 1,048,576 elems = 10 MB)
  const size_t QK = (size_t)2 * 8 * 2048 * 32;
  f16* Qs = (f16*)d_ws;
  f16* Ks = Qs + QK;
  f16* Qa = Ks + QK;
  f16* Ka = Qa + QK;
  f16* xt = Ka + QK;
  float* out     = (float*)d_out;
  float* out_cls = out + (size_t)2 * 2048 * 2048;
  float* attn0   = out_cls + 2 * 2048;

  k_transpose<<<dim3(32, 4, 2), 256, 0, stream>>>(x, xt);
  k_proj<<<dim3(64, 8, 2), 256, 0, stream>>>(x, af, Wq, Wa, Qs, Ks, Qa, Ka);
  k_flash<<<dim3(32, 8, 2), 256, 0, stream>>>(Qs, Ks, Qa, Ka, xt, out, out_cls);
  k_attn0<<<dim3(8, 2), 256, 0, stream>>>(Qs, Ks, Qa, Ka, attn0);
}

// Round 2
// 187.826 us; speedup vs baseline: 1.0695x; 1.0695x over previous
//
#include <hip/hip_runtime.h>

typedef _Float16 f16;
typedef _Float16 f16x4 __attribute__((ext_vector_type(4)));
typedef _Float16 f16x8 __attribute__((ext_vector_type(8)));
typedef float f32x4 __attribute__((ext_vector_type(4)));

#define LOG2E 1.4426950408889634f
#define SCL   (1.4426950408889634f / 32.0f)   // SCALE^2 * log2(e) folded

// ---------------- K0: transpose x[b][2048][256] f32 -> xt[b][256][2048] f16 --
__global__ __launch_bounds__(256) void k_transpose(const float* __restrict__ x,
                                                   f16* __restrict__ xt) {
  __shared__ f16 tile[64][65];
  int n0 = blockIdx.x * 64;
  int d0 = blockIdx.y * 64;
  int b  = blockIdx.z;
  int t = threadIdx.x;
  int colr = t & 63, rowg = t >> 6;
#pragma unroll
  for (int r = 0; r < 16; ++r) {
    int row = r * 4 + rowg;
    tile[row][colr] = (f16)x[((size_t)b * 2048 + n0 + row) * 256 + d0 + colr];
  }
  __syncthreads();
#pragma unroll
  for (int r = 0; r < 16; ++r) {
    int drow = r * 4 + rowg;
    xt[((size_t)b * 256 + d0 + drow) * 2048 + n0 + colr] = tile[colr][drow];
  }
}

// ---------------- K0b: W[s][256][768] f32 -> Wt[s][512][256] f16 (Q|K cols) --
__global__ __launch_bounds__(256) void k_transW(const float* __restrict__ Wq,
    const float* __restrict__ Wa, f16* __restrict__ Wt) {
  __shared__ f16 tile[64][65];
  int n0 = blockIdx.x * 64, k0 = blockIdx.y * 64, s = blockIdx.z;
  const float* W = s ? Wa : Wq;
  f16* dst = Wt + (size_t)s * 512 * 256;
  int t = threadIdx.x, c = t & 63, rg = t >> 6;
#pragma unroll
  for (int r = 0; r < 16; ++r) {
    int krow = r * 4 + rg;
    tile[krow][c] = (f16)W[(size_t)(k0 + krow) * 768 + n0 + c];
  }
  __syncthreads();
#pragma unroll
  for (int r = 0; r < 16; ++r) {
    int nrow = r * 4 + rg;
    dst[(size_t)(n0 + nrow) * 256 + k0 + c] = tile[c][nrow];
  }
}

// ---------------- K1: Q/K projections, global-direct (no LDS) ---------------
// Out: Q*/K* as [b*8+h][2048][32] f16.
__global__ __launch_bounds__(256) void k_proj(const float* __restrict__ x,
    const float* __restrict__ af, const f16* __restrict__ Wt,
    f16* __restrict__ Qs, f16* __restrict__ Ks,
    f16* __restrict__ Qa, f16* __restrict__ Ka) {
  int mt = blockIdx.x, nt = blockIdx.y, s = blockIdx.z;
  const float* A = s ? af : x;
  const f16* W = Wt + (size_t)s * 512 * 256;
  f16* Qd = s ? Qa : Qs;
  f16* Kd = s ? Ka : Ks;
  int t = threadIdx.x, wv = t >> 6, ln = t & 63, cl = ln & 15, g = ln >> 4;
  int m0 = mt * 64, n0 = nt * 64;
  const float* arow = A + (size_t)(m0 + wv * 16 + cl) * 256 + g * 8;
  const f16* wb = W + (size_t)n0 * 256 + g * 8;
  f32x4 z4 = {0.f, 0.f, 0.f, 0.f};
  f32x4 acc[4] = {z4, z4, z4, z4};
#pragma unroll
  for (int k32 = 0; k32 < 8; ++k32) {
    float4 u = *(const float4*)(arow + k32 * 32);
    float4 v = *(const float4*)(arow + k32 * 32 + 4);
    f16x8 a = { (f16)u.x, (f16)u.y, (f16)u.z, (f16)u.w,
                (f16)v.x, (f16)v.y, (f16)v.z, (f16)v.w };
#pragma unroll
    for (int n4 = 0; n4 < 4; ++n4) {
      f16x8 bf = *(const f16x8*)(wb + (size_t)(n4 * 16 + cl) * 256 + k32 * 32);
      acc[n4] = __builtin_amdgcn_mfma_f32_16x16x32_f16(a, bf, acc[n4], 0, 0, 0);
    }
  }
#pragma unroll
  for (int n4 = 0; n4 < 4; ++n4) {
    int c = n0 + n4 * 16 + cl;               // 0..511 (Q: 0-255, K: 256-511)
    int head = (c & 255) >> 5, d = c & 31;
    f16* dst = (c < 256) ? Qd : Kd;
#pragma unroll
    for (int r = 0; r < 4; ++r) {
      int m = m0 + wv * 16 + g * 4 + r;
      int bb = m >> 11, nn = m & 2047;
      dst[(((size_t)bb * 8 + head) * 2048 + nn) * 32 + d] = (f16)acc[n4][r];
    }
  }
}

// ---------------- K2: fused dual-score flash attention ----------------------
// Block = 4 waves, 64 q-rows. Wave wv: scores for q-stripe wv (16 rows),
// PV for all 64 q-rows x dd slice [wv*64, wv*64+64). KV tile = 64 keys.
// K tiles double-buffered in LDS (1 barrier/iter); Xt frags direct from L2.
__global__ __launch_bounds__(256) void k_flash(const f16* __restrict__ Qs,
    const f16* __restrict__ Ks, const f16* __restrict__ Qa,
    const f16* __restrict__ Ka, const f16* __restrict__ xt,
    float* __restrict__ out, float* __restrict__ out_cls) {
  __shared__ f16 KaL[2][64][40];     // pitch 80B: conflict-free A-frag reads
  __shared__ f16 KsL[2][64][40];
  __shared__ f16 PL[2][64][72];      // [q][j], pitch 144B
  __shared__ float alphaL[2][64];
  __shared__ float lL[64];
  int qt = blockIdx.x, h = blockIdx.y, b = blockIdx.z;
  int bh = b * 8 + h;
  int t = threadIdx.x, wv = t >> 6, ln = t & 63, cl = ln & 15, g = ln >> 4;
  int qrow0 = qt * 64 + wv * 16;
  f16x8 qsf = *(const f16x8*)&Qs[((size_t)bh * 2048 + qrow0 + cl) * 32 + g * 8];
  f16x8 qaf = *(const f16x8*)&Qa[((size_t)bh * 2048 + qrow0 + cl) * 32 + g * 8];
  f32x4 z4 = {0.f, 0.f, 0.f, 0.f};
  f32x4 acc[4][4];                   // [qt2][ddt]; D rows=q (g*4+r), cols=dd (cl)
#pragma unroll
  for (int i = 0; i < 4; ++i)
#pragma unroll
    for (int j = 0; j < 4; ++j) acc[i][j] = z4;
  float m_run = -3.0e38f, l_run = 0.f;
  int krow = t >> 2, koff = (t & 3) * 8;
  const f16* kaSrc = Ka + ((size_t)bh * 2048 + krow) * 32 + koff;
  const f16* ksSrc = Ks + ((size_t)bh * 2048 + krow) * 32 + koff;
  const f16* xb = xt + ((size_t)b * 256 + wv * 64) * 2048;

  // prologue: stage K tile 0
  *(f16x8*)&KaL[0][krow][koff] = *(const f16x8*)kaSrc;
  *(f16x8*)&KsL[0][krow][koff] = *(const f16x8*)ksSrc;
  __syncthreads();

  for (int kt = 0; kt < 32; ++kt) {
    int buf = kt & 1;
    // prefetch next K tile into regs (ds-write just before the barrier)
    f16x8 kan, ksn;
    if (kt < 31) {
      kan = *(const f16x8*)(kaSrc + (size_t)(kt + 1) * 2048);
      ksn = *(const f16x8*)(ksSrc + (size_t)(kt + 1) * 2048);
    }
    // prefetch this iter's Xt B-frags straight from global (L2-resident)
    f16x8 xf[2][4];
#pragma unroll
    for (int ks2 = 0; ks2 < 2; ++ks2)
#pragma unroll
      for (int ddt = 0; ddt < 4; ++ddt)
        xf[ks2][ddt] = *(const f16x8*)(xb + (size_t)(ddt * 16 + cl) * 2048 +
                                       kt * 64 + ks2 * 32 + g * 8);
    // --- dual QK^T (S^T tiles: A=K rows j, B=Q) ---
    float p[16];
    float tmax = -3.0e38f;
#pragma unroll
    for (int jt = 0; jt < 4; ++jt) {
      f16x8 kaf = *(const f16x8*)&KaL[buf][jt * 16 + cl][g * 8];
      f16x8 ksf = *(const f16x8*)&KsL[buf][jt * 16 + cl][g * 8];
      f32x4 za = __builtin_amdgcn_mfma_f32_16x16x32_f16(kaf, qaf, z4, 0, 0, 0);
      f32x4 zs = __builtin_amdgcn_mfma_f32_16x16x32_f16(ksf, qsf, z4, 0, 0, 0);
#pragma unroll
      for (int r = 0; r < 4; ++r) {
        float sv = za[r] * zs[r] * SCL;    // already in log2 domain
        p[jt * 4 + r] = sv;
        tmax = fmaxf(tmax, sv);
      }
    }
    tmax = fmaxf(tmax, __shfl_xor(tmax, 16, 64));
    tmax = fmaxf(tmax, __shfl_xor(tmax, 32, 64));
    float m_new = fmaxf(m_run, tmax);
    float alpha = exp2f(m_run - m_new);    // exactly 1.0 when max unchanged
    float lsum = 0.f;
#pragma unroll
    for (int q = 0; q < 16; ++q) {
      p[q] = exp2f(p[q] - m_new);
      lsum += p[q];
    }
    lsum += __shfl_xor(lsum, 16, 64);
    lsum += __shfl_xor(lsum, 32, 64);
    l_run = l_run * alpha + lsum;
    m_run = m_new;
    // commit staged K(kt+1)
    if (kt < 31) {
      *(f16x8*)&KaL[buf ^ 1][krow][koff] = kan;
      *(f16x8*)&KsL[buf ^ 1][krow][koff] = ksn;
    }
    // P -> LDS in A-operand layout [q][j]
#pragma unroll
    for (int jt = 0; jt < 4; ++jt) {
      f16x4 pk = { (f16)p[jt * 4 + 0], (f16)p[jt * 4 + 1],
                   (f16)p[jt * 4 + 2], (f16)p[jt * 4 + 3] };
      *(f16x4*)&PL[buf][wv * 16 + cl][jt * 16 + g * 4] = pk;
    }
    if (g == 0) alphaL[buf][wv * 16 + cl] = alpha;
    __syncthreads();
    // --- PV: O[q][dd] += P[q][j] * Xt[dd][j], wave's 64-dd slice ---
    float av[4][4];
    int need = 0;
#pragma unroll
    for (int qt2 = 0; qt2 < 4; ++qt2)
#pragma unroll
      for (int r = 0; r < 4; ++r) {
        float a = alphaL[buf][qt2 * 16 + g * 4 + r];
        av[qt2][r] = a;
        need |= (a != 1.0f);
      }
    if (__any(need)) {
#pragma unroll
      for (int qt2 = 0; qt2 < 4; ++qt2)
#pragma unroll
        for (int ddt = 0; ddt < 4; ++ddt)
#pragma unroll
          for (int r = 0; r < 4; ++r) acc[qt2][ddt][r] *= av[qt2][r];
    }
#pragma unroll
    for (int ks2 = 0; ks2 < 2; ++ks2) {
      f16x8 pf[4];
#pragma unroll
      for (int qt2 = 0; qt2 < 4; ++qt2)
        pf[qt2] = *(const f16x8*)&PL[buf][qt2 * 16 + cl][ks2 * 32 + g * 8];
#pragma unroll
      for (int ddt = 0; ddt < 4; ++ddt)
#pragma unroll
        for (int qt2 = 0; qt2 < 4; ++qt2)
          acc[qt2][ddt] = __builtin_amdgcn_mfma_f32_16x16x32_f16(
              pf[qt2], xf[ks2][ddt], acc[qt2][ddt], 0, 0, 0);
    }
  }
  // epilogue
  if (g == 0) lL[wv * 16 + cl] = l_run;
  __syncthreads();
#pragma unroll
  for (int qt2 = 0; qt2 < 4; ++qt2) {
#pragma unroll
    for (int r = 0; r < 4; ++r) {
      float linv = 1.0f / lL[qt2 * 16 + g * 4 + r];
      int q = qt * 64 + qt2 * 16 + g * 4 + r;
#pragma unroll
      for (int ddt = 0; ddt < 4; ++ddt) {
        float v = acc[qt2][ddt][r] * linv;
        int col = h * 256 + wv * 64 + ddt * 16 + cl;
        out[((size_t)b * 2048 + q) * 2048 + col] = v;
        if (q == 0) out_cls[(size_t)b * 2048 + col] = v;
      }
    }
  }
}

// ---------------- K3: attention probs for query row 0 (output 2) ------------
__global__ __launch_bounds__(256) void k_attn0(const f16* __restrict__ Qs,
    const f16* __restrict__ Ks, const f16* __restrict__ Qa,
    const f16* __restrict__ Ka, float* __restrict__ dst) {
  __shared__ float qa_s[32], qs_s[32];
  __shared__ float red[256];
  int h = blockIdx.x, b = blockIdx.y, bh = b * 8 + h;
  int t = threadIdx.x;
  if (t < 32) {
    qa_s[t] = (float)Qa[(size_t)bh * 2048 * 32 + t];
    qs_s[t] = (float)Qs[(size_t)bh * 2048 * 32 + t];
  }
  __syncthreads();
  float sv[8];
#pragma unroll
  for (int r = 0; r < 8; ++r) {
    int j = r * 256 + t;
    const f16x8* ka8 = (const f16x8*)&Ka[((size_t)bh * 2048 + j) * 32];
    const f16x8* ks8 = (const f16x8*)&Ks[((size_t)bh * 2048 + j) * 32];
    float da = 0.f, ds = 0.f;
#pragma unroll
    for (int c = 0; c < 4; ++c) {
      f16x8 va = ka8[c], vs = ks8[c];
#pragma unroll
      for (int d = 0; d < 8; ++d) {
        da += qa_s[c * 8 + d] * (float)va[d];
        ds += qs_s[c * 8 + d] * (float)vs[d];
      }
    }
    sv[r] = da * ds * (1.f / 32.f);
  }
  float mx = sv[0];
#pragma unroll
  for (int r = 1; r < 8; ++r) mx = fmaxf(mx, sv[r]);
  red[t] = mx;
  __syncthreads();
  for (int st = 128; st > 0; st >>= 1) {
    if (t < st) red[t] = fmaxf(red[t], red[t + st]);
    __syncthreads();
  }
  float m = red[0];
  __syncthreads();
  float e[8], sum = 0.f;
#pragma unroll
  for (int r = 0; r < 8; ++r) {
    e[r] = exp2f((sv[r] - m) * LOG2E);
    sum += e[r];
  }
  red[t] = sum;
  __syncthreads();
  for (int st = 128; st > 0; st >>= 1) {
    if (t < st) red[t] += red[t + st];
    __syncthreads();
  }
  float l = red[0];
#pragma unroll
  for (int r = 0; r < 8; ++r)
    dst[(size_t)b * 16384 + h * 2048 + r * 256 + t] = e[r] / l;
}

extern "C" void kernel_launch(void* const* d_in, const int* in_sizes, int n_in,
                              void* d_out, int out_size, void* d_ws, size_t ws_size,
                              hipStream_t stream) {
  const float* x  = (const float*)d_in[0];
  const float* af = (const float*)d_in[1];
  const float* Wq = (const float*)d_in[2];
  const float* Wa = (const float*)d_in[3];
  // ws (f16): Qs|Ks|Qa|Ka (4x1M) | xt (1M) | Wt (256K)  ~= 10.5 MB
  const size_t QK = (size_t)2 * 8 * 2048 * 32;
  f16* Qs = (f16*)d_ws;
  f16* Ks = Qs + QK;
  f16* Qa = Ks + QK;
  f16* Ka = Qa + QK;
  f16* xt = Ka + QK;
  f16* Wt = xt + QK;
  float* out     = (float*)d_out;
  float* out_cls = out + (size_t)2 * 2048 * 2048;
  float* attn0   = out_cls + 2 * 2048;

  k_transpose<<<dim3(32, 4, 2), 256, 0, stream>>>(x, xt);
  k_transW<<<dim3(8, 4, 2), 256, 0, stream>>>(Wq, Wa, Wt);
  k_proj<<<dim3(64, 8, 2), 256, 0, stream>>>(x, af, Wt, Qs, Ks, Qa, Ka);
  k_flash<<<dim3(32, 8, 2), 256, 0, stream>>>(Qs, Ks, Qa, Ka, xt, out, out_cls);
  k_attn0<<<dim3(8, 2), 256, 0, stream>>>(Qs, Ks, Qa, Ka, attn0);
}